// Round 6
// baseline (3937.789 us; speedup 1.0000x reference)
//
#include <hip/hip_runtime.h>

#define TT 2048
#define BB 128
#define DD 128
#define HH 256

typedef float f32x4 __attribute__((ext_vector_type(4)));
typedef _Float16 f16x8 __attribute__((ext_vector_type(8)));
typedef _Float16 f16x4 __attribute__((ext_vector_type(4)));

static __device__ __forceinline__ float fast_tanh(float s) {
    // tanh(s) = 1 - 2/(exp(2s)+1); exp->inf and ->0 both saturate correctly
    float e = __expf(2.0f * s);
    float r = __builtin_amdgcn_rcpf(e + 1.0f);
    return __builtin_fmaf(-2.0f, r, 1.0f);
}

// LDS-only barrier: cross-wave communication in the rec loop is exclusively
// through LDS, so drain lgkmcnt but NOT vmcnt (global h-stores / xp-loads stay
// in flight across the barrier). sched_barrier(0) fences per rule #18.
static __device__ __forceinline__ void lds_barrier() {
    __builtin_amdgcn_sched_barrier(0);
    asm volatile("s_waitcnt lgkmcnt(0)" ::: "memory");
    __builtin_amdgcn_s_barrier();
    __builtin_amdgcn_sched_barrier(0);
}

// ---------------------------------------------------------------------------
// xproj: out[t,b,:] = x[t,b,:] @ W_in + (b_in + b_h), via f16 MFMA.
// (unchanged — ~97 us, ~4 TB/s)
// ---------------------------------------------------------------------------
__global__ __launch_bounds__(256, 2) void xproj_mfma(
    const float* __restrict__ x, const float* __restrict__ W_in,
    const float* __restrict__ b_in, const float* __restrict__ b_h,
    float* __restrict__ out)
{
    __shared__ short xs[64 * 128];  // f16 bits, swizzled, 16 KB
    const int tid  = threadIdx.x;
    const int lane = tid & 63;
    const int w    = tid >> 6;
    const int lrow = lane & 15;
    const int lgrp = lane >> 4;
    const long rbase = (long)blockIdx.x * 64;

    f16x8 bw[4][4];
    #pragma unroll
    for (int kc = 0; kc < 4; ++kc)
        #pragma unroll
        for (int nt = 0; nt < 4; ++nt) {
            const int n = w * 64 + nt * 16 + lrow;
            #pragma unroll
            for (int i = 0; i < 8; ++i)
                bw[kc][nt][i] = (_Float16)W_in[(kc * 32 + lgrp * 8 + i) * HH + n];
        }
    float bias[4];
    #pragma unroll
    for (int nt = 0; nt < 4; ++nt) {
        const int n = w * 64 + nt * 16 + lrow;
        bias[nt] = b_in[n] + b_h[n];
    }

    {
        const float4* xg = (const float4*)(x + rbase * DD);
        #pragma unroll
        for (int th = 0; th < 8; ++th) {
            int idx = tid + th * 256;
            int r   = idx >> 5;
            int c4  = idx & 31;
            float4 v = xg[idx];
            f16x4 p;
            p[0] = (_Float16)v.x; p[1] = (_Float16)v.y;
            p[2] = (_Float16)v.z; p[3] = (_Float16)v.w;
            unsigned off = (unsigned)(r * 256 + c4 * 8);
            off ^= (unsigned)((r & 7) << 4);
            *(f16x4*)((char*)xs + off) = p;
        }
    }
    __syncthreads();

    #pragma unroll
    for (int mt = 0; mt < 4; ++mt) {
        const int r = mt * 16 + lrow;
        f16x8 a[4];
        #pragma unroll
        for (int kc = 0; kc < 4; ++kc) {
            unsigned off = (unsigned)(r * 256 + kc * 64 + lgrp * 16);
            off ^= (unsigned)((r & 7) << 4);
            a[kc] = *(const f16x8*)((const char*)xs + off);
        }
        f32x4 acc[4];
        #pragma unroll
        for (int nt = 0; nt < 4; ++nt) { f32x4 c = {bias[nt], bias[nt], bias[nt], bias[nt]}; acc[nt] = c; }
        #pragma unroll
        for (int kc = 0; kc < 4; ++kc)
            #pragma unroll
            for (int nt = 0; nt < 4; ++nt)
                acc[nt] = __builtin_amdgcn_mfma_f32_16x16x32_f16(a[kc], bw[kc][nt], acc[nt], 0, 0, 0);
        #pragma unroll
        for (int nt = 0; nt < 4; ++nt)
            #pragma unroll
            for (int rr = 0; rr < 4; ++rr)
                out[(rbase + mt * 16 + lgrp * 4 + rr) * HH + w * 64 + nt * 16 + lrow] = acc[nt][rr];
    }
}

// ---------------------------------------------------------------------------
// Recurrence: 4 WGs x 32 batch rows = TWO independent 16-row groups (A,B) per
// WG, advanced alternately with ONE barrier per period (2 rec-steps/barrier).
// 512 threads = 8 waves (2/SIMD); wave w owns h-cols [w*32, w*32+32).
// D[j][g] = sum_k W_h[k][j] h[g][k]; A-op = W_h^T f16 static in VGPRs (64),
// B-op = h f16 in swizzled LDS (4 buffers). C-init = xproj prefetched 2
// periods ahead, UNCLAMPED in the main loop (provably no-alias vs the h
// stores: constant 2*BB*HH offset), last 2 periods peeled with no loads.
// Global h stores issued AFTER the barrier (off the serial path).
// ---------------------------------------------------------------------------
template<bool PF>
static __device__ __forceinline__ void rec_period(
    float* io, int p, int b0A, int b0B, int lrow, int lgrp, int jb,
    f32x4 (&xqA)[2], f32x4 (&xqB)[2],
    const short* curA, short* nxtA, const short* curB, short* nxtB,
    const f16x8 (&wh)[2][8])
{
    f32x4 hvA[2], hvB[2];

    // ---------------- group A step ----------------
    {
        f16x8 bbf[8];
        #pragma unroll
        for (int kc = 0; kc < 8; ++kc) {
            unsigned off = (unsigned)(lrow * 512 + kc * 64 + lgrp * 16) ^ (unsigned)((lrow & 7) << 4);
            bbf[kc] = *(const f16x8*)((const char*)curA + off);
        }
        f32x4 acc0[2], acc1[2];
        #pragma unroll
        for (int mt = 0; mt < 2; ++mt) {
            acc0[mt] = xqA[mt];
            f32x4 z = {0.f, 0.f, 0.f, 0.f};
            acc1[mt] = z;
        }
        if (PF) {
            #pragma unroll
            for (int mt = 0; mt < 2; ++mt)
                xqA[mt] = *(const f32x4*)(io + ((long)(p + 2) * BB + b0A + lrow) * HH + jb + mt * 16 + lgrp * 4);
        }
        #pragma unroll
        for (int kc = 0; kc < 4; ++kc)
            #pragma unroll
            for (int mt = 0; mt < 2; ++mt) {
                acc0[mt] = __builtin_amdgcn_mfma_f32_16x16x32_f16(wh[mt][kc],     bbf[kc],     acc0[mt], 0, 0, 0);
                acc1[mt] = __builtin_amdgcn_mfma_f32_16x16x32_f16(wh[mt][kc + 4], bbf[kc + 4], acc1[mt], 0, 0, 0);
            }
        #pragma unroll
        for (int mt = 0; mt < 2; ++mt) {
            f32x4 s4 = acc0[mt] + acc1[mt];
            #pragma unroll
            for (int rr = 0; rr < 4; ++rr) hvA[mt][rr] = fast_tanh(s4[rr]);
            f16x4 q;
            #pragma unroll
            for (int rr = 0; rr < 4; ++rr) q[rr] = (_Float16)hvA[mt][rr];
            unsigned off = (unsigned)(lrow * 512 + (jb + mt * 16 + lgrp * 4) * 2) ^ (unsigned)((lrow & 7) << 4);
            *(f16x4*)((char*)nxtA + off) = q;
        }
    }
    // ---------------- group B step ----------------
    {
        f16x8 bbf[8];
        #pragma unroll
        for (int kc = 0; kc < 8; ++kc) {
            unsigned off = (unsigned)(lrow * 512 + kc * 64 + lgrp * 16) ^ (unsigned)((lrow & 7) << 4);
            bbf[kc] = *(const f16x8*)((const char*)curB + off);
        }
        f32x4 acc0[2], acc1[2];
        #pragma unroll
        for (int mt = 0; mt < 2; ++mt) {
            acc0[mt] = xqB[mt];
            f32x4 z = {0.f, 0.f, 0.f, 0.f};
            acc1[mt] = z;
        }
        if (PF) {
            #pragma unroll
            for (int mt = 0; mt < 2; ++mt)
                xqB[mt] = *(const f32x4*)(io + ((long)(p + 2) * BB + b0B + lrow) * HH + jb + mt * 16 + lgrp * 4);
        }
        #pragma unroll
        for (int kc = 0; kc < 4; ++kc)
            #pragma unroll
            for (int mt = 0; mt < 2; ++mt) {
                acc0[mt] = __builtin_amdgcn_mfma_f32_16x16x32_f16(wh[mt][kc],     bbf[kc],     acc0[mt], 0, 0, 0);
                acc1[mt] = __builtin_amdgcn_mfma_f32_16x16x32_f16(wh[mt][kc + 4], bbf[kc + 4], acc1[mt], 0, 0, 0);
            }
        #pragma unroll
        for (int mt = 0; mt < 2; ++mt) {
            f32x4 s4 = acc0[mt] + acc1[mt];
            #pragma unroll
            for (int rr = 0; rr < 4; ++rr) hvB[mt][rr] = fast_tanh(s4[rr]);
            f16x4 q;
            #pragma unroll
            for (int rr = 0; rr < 4; ++rr) q[rr] = (_Float16)hvB[mt][rr];
            unsigned off = (unsigned)(lrow * 512 + (jb + mt * 16 + lgrp * 4) * 2) ^ (unsigned)((lrow & 7) << 4);
            *(f16x4*)((char*)nxtB + off) = q;
        }
    }

    lds_barrier();

    // global h stores AFTER the barrier: overlap next period's reads/MFMA
    #pragma unroll
    for (int mt = 0; mt < 2; ++mt) {
        *(f32x4*)(io + ((long)p * BB + b0A + lrow) * HH + jb + mt * 16 + lgrp * 4) = hvA[mt];
        *(f32x4*)(io + ((long)p * BB + b0B + lrow) * HH + jb + mt * 16 + lgrp * 4) = hvB[mt];
    }
}

__global__ __launch_bounds__(512, 2) void rnn_rec_mfma(
    const float* __restrict__ h0, const float* __restrict__ W_h,
    float* io)
{
    __shared__ short hA0[16 * 256], hA1[16 * 256];  // group A h buffers (8 KB each)
    __shared__ short hB0[16 * 256], hB1[16 * 256];  // group B
    const int tid  = threadIdx.x;
    const int lane = tid & 63;
    const int w    = tid >> 6;       // 0..7
    const int lrow = lane & 15;
    const int lgrp = lane >> 4;
    const int b0A  = blockIdx.x * 32;
    const int b0B  = b0A + 16;
    const int jb   = w * 32;

    // A-frags: A[j][k] = W_h[k][j], j = jb + mt*16 + lrow, k = kc*32 + lgrp*8 + i
    f16x8 wh[2][8];
    #pragma unroll
    for (int mt = 0; mt < 2; ++mt) {
        const int j = jb + mt * 16 + lrow;
        #pragma unroll
        for (int kc = 0; kc < 8; ++kc)
            #pragma unroll
            for (int i = 0; i < 8; ++i)
                wh[mt][kc][i] = (_Float16)W_h[(kc * 32 + lgrp * 8 + i) * HH + j];
    }

    // h0 -> hA0/hB0 (fp32 -> f16, swizzled [g][k] layout)
    {
        const int g  = tid >> 4;            // 0..31
        const int k0 = (tid & 15) * 16;     // 16 f16 per thread
        const float* hp = h0 + (b0A + g) * HH + k0;
        f16x8 p0, p1;
        #pragma unroll
        for (int i = 0; i < 8; ++i) { p0[i] = (_Float16)hp[i]; p1[i] = (_Float16)hp[8 + i]; }
        short* buf = (g < 16) ? hA0 : hB0;
        const int gl = g & 15;
        unsigned off0 = (unsigned)(gl * 512 + k0 * 2)      ^ (unsigned)((gl & 7) << 4);
        unsigned off1 = (unsigned)(gl * 512 + k0 * 2 + 16) ^ (unsigned)((gl & 7) << 4);
        *(f16x8*)((char*)buf + off0) = p0;
        *(f16x8*)((char*)buf + off1) = p1;
    }

    // xp preload (C-init) for periods 0 and 1, both groups
    f32x4 xqA0[2], xqA1[2], xqB0[2], xqB1[2];
    #pragma unroll
    for (int mt = 0; mt < 2; ++mt) {
        const long o = (long)(b0A + lrow) * HH + jb + mt * 16 + lgrp * 4;
        const long oB = (long)(b0B + lrow) * HH + jb + mt * 16 + lgrp * 4;
        xqA0[mt] = *(const f32x4*)(io + (long)0 * BB * HH + o);
        xqA1[mt] = *(const f32x4*)(io + (long)1 * BB * HH + o);
        xqB0[mt] = *(const f32x4*)(io + (long)0 * BB * HH + oB);
        xqB1[mt] = *(const f32x4*)(io + (long)1 * BB * HH + oB);
    }

    __syncthreads();

    for (int p = 0; p < TT - 2; p += 2) {
        rec_period<true>(io, p,     b0A, b0B, lrow, lgrp, jb, xqA0, xqB0, hA0, hA1, hB0, hB1, wh);
        rec_period<true>(io, p + 1, b0A, b0B, lrow, lgrp, jb, xqA1, xqB1, hA1, hA0, hB1, hB0, wh);
    }
    // peeled final two periods: no prefetch loads (avoids OOB and aliasing)
    rec_period<false>(io, TT - 2, b0A, b0B, lrow, lgrp, jb, xqA0, xqB0, hA0, hA1, hB0, hB1, wh);
    rec_period<false>(io, TT - 1, b0A, b0B, lrow, lgrp, jb, xqA1, xqB1, hA1, hA0, hB1, hB0, wh);
}

extern "C" void kernel_launch(void* const* d_in, const int* in_sizes, int n_in,
                              void* d_out, int out_size, void* d_ws, size_t ws_size,
                              hipStream_t stream) {
    const float* x    = (const float*)d_in[0];
    const float* h0   = (const float*)d_in[1];
    const float* W_in = (const float*)d_in[2];
    const float* b_in = (const float*)d_in[3];
    const float* W_h  = (const float*)d_in[4];
    const float* b_h  = (const float*)d_in[5];
    float* out = (float*)d_out;

    xproj_mfma<<<(TT * BB) / 64, 256, 0, stream>>>(x, W_in, b_in, b_h, out);
    rnn_rec_mfma<<<BB / 32, 512, 0, stream>>>(h0, W_h, out);
}

// Round 7
// 3884.032 us; speedup vs baseline: 1.0138x; 1.0138x over previous
//
#include <hip/hip_runtime.h>

#define TT 2048
#define BB 128
#define DD 128
#define HH 256

typedef float f32x4 __attribute__((ext_vector_type(4)));
typedef _Float16 f16x8 __attribute__((ext_vector_type(8)));
typedef _Float16 f16x4 __attribute__((ext_vector_type(4)));

static __device__ __forceinline__ float fast_tanh(float s) {
    // tanh(s) = 1 - 2/(exp(2s)+1); exp->inf and ->0 both saturate correctly
    float e = __expf(2.0f * s);
    float r = __builtin_amdgcn_rcpf(e + 1.0f);
    return __builtin_fmaf(-2.0f, r, 1.0f);
}

// LDS-only barrier: cross-wave communication in the rec loop is exclusively
// through LDS, so drain lgkmcnt but NOT vmcnt (global h-stores / xp-loads stay
// in flight across the barrier). sched_barrier(0) fences per rule #18.
static __device__ __forceinline__ void lds_barrier() {
    __builtin_amdgcn_sched_barrier(0);
    asm volatile("s_waitcnt lgkmcnt(0)" ::: "memory");
    __builtin_amdgcn_s_barrier();
    __builtin_amdgcn_sched_barrier(0);
}

// ---------------------------------------------------------------------------
// xproj: out[t,b,:] = x[t,b,:] @ W_in + (b_in + b_h), via f16 MFMA.
// (unchanged — ~100 us)
// ---------------------------------------------------------------------------
__global__ __launch_bounds__(256, 2) void xproj_mfma(
    const float* __restrict__ x, const float* __restrict__ W_in,
    const float* __restrict__ b_in, const float* __restrict__ b_h,
    float* __restrict__ out)
{
    __shared__ short xs[64 * 128];  // f16 bits, swizzled, 16 KB
    const int tid  = threadIdx.x;
    const int lane = tid & 63;
    const int w    = tid >> 6;
    const int lrow = lane & 15;
    const int lgrp = lane >> 4;
    const long rbase = (long)blockIdx.x * 64;

    f16x8 bw[4][4];
    #pragma unroll
    for (int kc = 0; kc < 4; ++kc)
        #pragma unroll
        for (int nt = 0; nt < 4; ++nt) {
            const int n = w * 64 + nt * 16 + lrow;
            #pragma unroll
            for (int i = 0; i < 8; ++i)
                bw[kc][nt][i] = (_Float16)W_in[(kc * 32 + lgrp * 8 + i) * HH + n];
        }
    float bias[4];
    #pragma unroll
    for (int nt = 0; nt < 4; ++nt) {
        const int n = w * 64 + nt * 16 + lrow;
        bias[nt] = b_in[n] + b_h[n];
    }

    {
        const float4* xg = (const float4*)(x + rbase * DD);
        #pragma unroll
        for (int th = 0; th < 8; ++th) {
            int idx = tid + th * 256;
            int r   = idx >> 5;
            int c4  = idx & 31;
            float4 v = xg[idx];
            f16x4 p;
            p[0] = (_Float16)v.x; p[1] = (_Float16)v.y;
            p[2] = (_Float16)v.z; p[3] = (_Float16)v.w;
            unsigned off = (unsigned)(r * 256 + c4 * 8);
            off ^= (unsigned)((r & 7) << 4);
            *(f16x4*)((char*)xs + off) = p;
        }
    }
    __syncthreads();

    #pragma unroll
    for (int mt = 0; mt < 4; ++mt) {
        const int r = mt * 16 + lrow;
        f16x8 a[4];
        #pragma unroll
        for (int kc = 0; kc < 4; ++kc) {
            unsigned off = (unsigned)(r * 256 + kc * 64 + lgrp * 16);
            off ^= (unsigned)((r & 7) << 4);
            a[kc] = *(const f16x8*)((const char*)xs + off);
        }
        f32x4 acc[4];
        #pragma unroll
        for (int nt = 0; nt < 4; ++nt) { f32x4 c = {bias[nt], bias[nt], bias[nt], bias[nt]}; acc[nt] = c; }
        #pragma unroll
        for (int kc = 0; kc < 4; ++kc)
            #pragma unroll
            for (int nt = 0; nt < 4; ++nt)
                acc[nt] = __builtin_amdgcn_mfma_f32_16x16x32_f16(a[kc], bw[kc][nt], acc[nt], 0, 0, 0);
        #pragma unroll
        for (int nt = 0; nt < 4; ++nt)
            #pragma unroll
            for (int rr = 0; rr < 4; ++rr)
                out[(rbase + mt * 16 + lgrp * 4 + rr) * HH + w * 64 + nt * 16 + lrow] = acc[nt][rr];
    }
}

// ---------------------------------------------------------------------------
// Recurrence: 4 WGs x 32 batch rows = two independent 16-row groups (A,B),
// ONE barrier per period (one timestep for BOTH groups), with A and B
// MANUALLY INTERLEAVED phase-by-phase so their pipes overlap:
//   {readA||readB} -> {8 MFMA chains A/B-interleaved} -> {tanh/pack/ldswrite
//   A/B-interleaved} -> barrier -> global stores.
// 512 threads = 8 waves (2/SIMD); wave w owns h-cols [w*32, w*32+32).
// D[j][g] = sum_k W_h[k][j] h[g][k]; W_h^T f16 static in VGPRs (shared by A,B).
// K-split per group: kc0..3 -> acc[.][0], kc4..7 -> acc[.][1] (8 chains total).
// C-init = xproj prefetched 2 periods ahead (unclamped in main loop; last two
// periods peeled). h_t overwrites xp_t in d_out after the barrier.
// ---------------------------------------------------------------------------
template<bool PF>
static __device__ __forceinline__ void rec_period(
    float* io, int p, int b0A, int b0B, int lrow, int lgrp, int jb,
    f32x4 (&xqA)[2], f32x4 (&xqB)[2],
    const short* curA, short* nxtA, const short* curB, short* nxtB,
    const f16x8 (&wh)[2][8])
{
    // ---- phase 1: interleaved LDS reads (A and B in flight together) ----
    f16x8 bbfA[8], bbfB[8];
    #pragma unroll
    for (int kc = 0; kc < 8; ++kc) {
        unsigned off = (unsigned)(lrow * 512 + kc * 64 + lgrp * 16) ^ (unsigned)((lrow & 7) << 4);
        bbfA[kc] = *(const f16x8*)((const char*)curA + off);
        bbfB[kc] = *(const f16x8*)((const char*)curB + off);
    }

    // ---- acc init + xp prefetch for p+2 ----
    f32x4 accA[2][2], accB[2][2];
    #pragma unroll
    for (int mt = 0; mt < 2; ++mt) {
        f32x4 z = {0.f, 0.f, 0.f, 0.f};
        accA[mt][0] = xqA[mt];  accA[mt][1] = z;
        accB[mt][0] = xqB[mt];  accB[mt][1] = z;
    }
    if (PF) {
        #pragma unroll
        for (int mt = 0; mt < 2; ++mt) {
            xqA[mt] = *(const f32x4*)(io + ((long)(p + 2) * BB + b0A + lrow) * HH + jb + mt * 16 + lgrp * 4);
            xqB[mt] = *(const f32x4*)(io + ((long)(p + 2) * BB + b0B + lrow) * HH + jb + mt * 16 + lgrp * 4);
        }
    }

    // ---- phase 2: 8 independent MFMA chains, A/B interleaved per-op ----
    #pragma unroll
    for (int kc = 0; kc < 4; ++kc) {
        accA[0][0] = __builtin_amdgcn_mfma_f32_16x16x32_f16(wh[0][kc],     bbfA[kc],     accA[0][0], 0, 0, 0);
        accB[0][0] = __builtin_amdgcn_mfma_f32_16x16x32_f16(wh[0][kc],     bbfB[kc],     accB[0][0], 0, 0, 0);
        accA[1][0] = __builtin_amdgcn_mfma_f32_16x16x32_f16(wh[1][kc],     bbfA[kc],     accA[1][0], 0, 0, 0);
        accB[1][0] = __builtin_amdgcn_mfma_f32_16x16x32_f16(wh[1][kc],     bbfB[kc],     accB[1][0], 0, 0, 0);
        accA[0][1] = __builtin_amdgcn_mfma_f32_16x16x32_f16(wh[0][kc + 4], bbfA[kc + 4], accA[0][1], 0, 0, 0);
        accB[0][1] = __builtin_amdgcn_mfma_f32_16x16x32_f16(wh[0][kc + 4], bbfB[kc + 4], accB[0][1], 0, 0, 0);
        accA[1][1] = __builtin_amdgcn_mfma_f32_16x16x32_f16(wh[1][kc + 4], bbfA[kc + 4], accA[1][1], 0, 0, 0);
        accB[1][1] = __builtin_amdgcn_mfma_f32_16x16x32_f16(wh[1][kc + 4], bbfB[kc + 4], accB[1][1], 0, 0, 0);
    }

    // ---- phase 3: tanh + pack + LDS write, A/B interleaved ----
    f32x4 hvA[2], hvB[2];
    #pragma unroll
    for (int mt = 0; mt < 2; ++mt) {
        f32x4 sA = accA[mt][0] + accA[mt][1];
        f32x4 sB = accB[mt][0] + accB[mt][1];
        #pragma unroll
        for (int rr = 0; rr < 4; ++rr) {
            hvA[mt][rr] = fast_tanh(sA[rr]);
            hvB[mt][rr] = fast_tanh(sB[rr]);
        }
        f16x4 qA, qB;
        #pragma unroll
        for (int rr = 0; rr < 4; ++rr) { qA[rr] = (_Float16)hvA[mt][rr]; qB[rr] = (_Float16)hvB[mt][rr]; }
        unsigned off = (unsigned)(lrow * 512 + (jb + mt * 16 + lgrp * 4) * 2) ^ (unsigned)((lrow & 7) << 4);
        *(f16x4*)((char*)nxtA + off) = qA;
        *(f16x4*)((char*)nxtB + off) = qB;
    }

    lds_barrier();

    // ---- global h stores AFTER the barrier (off the serial path) ----
    #pragma unroll
    for (int mt = 0; mt < 2; ++mt) {
        *(f32x4*)(io + ((long)p * BB + b0A + lrow) * HH + jb + mt * 16 + lgrp * 4) = hvA[mt];
        *(f32x4*)(io + ((long)p * BB + b0B + lrow) * HH + jb + mt * 16 + lgrp * 4) = hvB[mt];
    }
}

__global__ __launch_bounds__(512, 2) void rnn_rec_mfma(
    const float* __restrict__ h0, const float* __restrict__ W_h,
    float* io)
{
    __shared__ short hA0[16 * 256], hA1[16 * 256];  // group A h buffers (8 KB each)
    __shared__ short hB0[16 * 256], hB1[16 * 256];  // group B
    const int tid  = threadIdx.x;
    const int lane = tid & 63;
    const int w    = tid >> 6;       // 0..7
    const int lrow = lane & 15;
    const int lgrp = lane >> 4;
    const int b0A  = blockIdx.x * 32;
    const int b0B  = b0A + 16;
    const int jb   = w * 32;

    // A-frags: A[j][k] = W_h[k][j], j = jb + mt*16 + lrow, k = kc*32 + lgrp*8 + i
    f16x8 wh[2][8];
    #pragma unroll
    for (int mt = 0; mt < 2; ++mt) {
        const int j = jb + mt * 16 + lrow;
        #pragma unroll
        for (int kc = 0; kc < 8; ++kc)
            #pragma unroll
            for (int i = 0; i < 8; ++i)
                wh[mt][kc][i] = (_Float16)W_h[(kc * 32 + lgrp * 8 + i) * HH + j];
    }

    // h0 -> hA0/hB0 (fp32 -> f16, swizzled [g][k] layout)
    {
        const int g  = tid >> 4;            // 0..31
        const int k0 = (tid & 15) * 16;     // 16 f16 per thread
        const float* hp = h0 + (b0A + g) * HH + k0;
        f16x8 p0, p1;
        #pragma unroll
        for (int i = 0; i < 8; ++i) { p0[i] = (_Float16)hp[i]; p1[i] = (_Float16)hp[8 + i]; }
        short* buf = (g < 16) ? hA0 : hB0;
        const int gl = g & 15;
        unsigned off0 = (unsigned)(gl * 512 + k0 * 2)      ^ (unsigned)((gl & 7) << 4);
        unsigned off1 = (unsigned)(gl * 512 + k0 * 2 + 16) ^ (unsigned)((gl & 7) << 4);
        *(f16x8*)((char*)buf + off0) = p0;
        *(f16x8*)((char*)buf + off1) = p1;
    }

    // xp preload (C-init) for periods 0 and 1, both groups
    f32x4 xqA0[2], xqA1[2], xqB0[2], xqB1[2];
    #pragma unroll
    for (int mt = 0; mt < 2; ++mt) {
        const long oA = (long)(b0A + lrow) * HH + jb + mt * 16 + lgrp * 4;
        const long oB = (long)(b0B + lrow) * HH + jb + mt * 16 + lgrp * 4;
        xqA0[mt] = *(const f32x4*)(io + (long)0 * BB * HH + oA);
        xqA1[mt] = *(const f32x4*)(io + (long)1 * BB * HH + oA);
        xqB0[mt] = *(const f32x4*)(io + (long)0 * BB * HH + oB);
        xqB1[mt] = *(const f32x4*)(io + (long)1 * BB * HH + oB);
    }

    __syncthreads();

    for (int p = 0; p < TT - 2; p += 2) {
        rec_period<true>(io, p,     b0A, b0B, lrow, lgrp, jb, xqA0, xqB0, hA0, hA1, hB0, hB1, wh);
        rec_period<true>(io, p + 1, b0A, b0B, lrow, lgrp, jb, xqA1, xqB1, hA1, hA0, hB1, hB0, wh);
    }
    // peeled final two periods: no prefetch loads (avoids OOB and aliasing)
    rec_period<false>(io, TT - 2, b0A, b0B, lrow, lgrp, jb, xqA0, xqB0, hA0, hA1, hB0, hB1, wh);
    rec_period<false>(io, TT - 1, b0A, b0B, lrow, lgrp, jb, xqA1, xqB1, hA1, hA0, hB1, hB0, wh);
}

extern "C" void kernel_launch(void* const* d_in, const int* in_sizes, int n_in,
                              void* d_out, int out_size, void* d_ws, size_t ws_size,
                              hipStream_t stream) {
    const float* x    = (const float*)d_in[0];
    const float* h0   = (const float*)d_in[1];
    const float* W_in = (const float*)d_in[2];
    const float* b_in = (const float*)d_in[3];
    const float* W_h  = (const float*)d_in[4];
    const float* b_h  = (const float*)d_in[5];
    float* out = (float*)d_out;

    xproj_mfma<<<(TT * BB) / 64, 256, 0, stream>>>(x, W_in, b_in, b_h, out);
    rnn_rec_mfma<<<BB / 32, 512, 0, stream>>>(h0, W_h, out);
}

// Round 9
// 2108.160 us; speedup vs baseline: 1.8679x; 1.8424x over previous
//
#include <hip/hip_runtime.h>

#define TT 2048
#define BB 128
#define DD 128
#define HH 256

typedef float f32x4 __attribute__((ext_vector_type(4)));
typedef _Float16 f16x8 __attribute__((ext_vector_type(8)));
typedef _Float16 f16x4 __attribute__((ext_vector_type(4)));

static __device__ __forceinline__ float fast_tanh(float s) {
    // tanh(s) = 1 - 2/(exp(2s)+1); exp->inf and ->0 both saturate correctly
    float e = __expf(2.0f * s);
    float r = __builtin_amdgcn_rcpf(e + 1.0f);
    return __builtin_fmaf(-2.0f, r, 1.0f);
}

// LDS-only barrier: cross-wave communication in the rec loop is exclusively
// through LDS, so drain lgkmcnt but NOT vmcnt (global h-stores / xp-loads stay
// in flight across the barrier). sched_barrier(0) fences per rule #18.
static __device__ __forceinline__ void lds_barrier() {
    __builtin_amdgcn_sched_barrier(0);
    asm volatile("s_waitcnt lgkmcnt(0)" ::: "memory");
    __builtin_amdgcn_s_barrier();
    __builtin_amdgcn_sched_barrier(0);
}

// ---------------------------------------------------------------------------
// xproj: out[t,b,:] = x[t,b,:] @ W_in + (b_in + b_h), via f16 MFMA.
// (unchanged — ~100 us)
// ---------------------------------------------------------------------------
__global__ __launch_bounds__(256, 2) void xproj_mfma(
    const float* __restrict__ x, const float* __restrict__ W_in,
    const float* __restrict__ b_in, const float* __restrict__ b_h,
    float* __restrict__ out)
{
    __shared__ short xs[64 * 128];  // f16 bits, swizzled, 16 KB
    const int tid  = threadIdx.x;
    const int lane = tid & 63;
    const int w    = tid >> 6;
    const int lrow = lane & 15;
    const int lgrp = lane >> 4;
    const long rbase = (long)blockIdx.x * 64;

    f16x8 bw[4][4];
    #pragma unroll
    for (int kc = 0; kc < 4; ++kc)
        #pragma unroll
        for (int nt = 0; nt < 4; ++nt) {
            const int n = w * 64 + nt * 16 + lrow;
            #pragma unroll
            for (int i = 0; i < 8; ++i)
                bw[kc][nt][i] = (_Float16)W_in[(kc * 32 + lgrp * 8 + i) * HH + n];
        }
    float bias[4];
    #pragma unroll
    for (int nt = 0; nt < 4; ++nt) {
        const int n = w * 64 + nt * 16 + lrow;
        bias[nt] = b_in[n] + b_h[n];
    }

    {
        const float4* xg = (const float4*)(x + rbase * DD);
        #pragma unroll
        for (int th = 0; th < 8; ++th) {
            int idx = tid + th * 256;
            int r   = idx >> 5;
            int c4  = idx & 31;
            float4 v = xg[idx];
            f16x4 p;
            p[0] = (_Float16)v.x; p[1] = (_Float16)v.y;
            p[2] = (_Float16)v.z; p[3] = (_Float16)v.w;
            unsigned off = (unsigned)(r * 256 + c4 * 8);
            off ^= (unsigned)((r & 7) << 4);
            *(f16x4*)((char*)xs + off) = p;
        }
    }
    __syncthreads();

    #pragma unroll
    for (int mt = 0; mt < 4; ++mt) {
        const int r = mt * 16 + lrow;
        f16x8 a[4];
        #pragma unroll
        for (int kc = 0; kc < 4; ++kc) {
            unsigned off = (unsigned)(r * 256 + kc * 64 + lgrp * 16);
            off ^= (unsigned)((r & 7) << 4);
            a[kc] = *(const f16x8*)((const char*)xs + off);
        }
        f32x4 acc[4];
        #pragma unroll
        for (int nt = 0; nt < 4; ++nt) { f32x4 c = {bias[nt], bias[nt], bias[nt], bias[nt]}; acc[nt] = c; }
        #pragma unroll
        for (int kc = 0; kc < 4; ++kc)
            #pragma unroll
            for (int nt = 0; nt < 4; ++nt)
                acc[nt] = __builtin_amdgcn_mfma_f32_16x16x32_f16(a[kc], bw[kc][nt], acc[nt], 0, 0, 0);
        #pragma unroll
        for (int nt = 0; nt < 4; ++nt)
            #pragma unroll
            for (int rr = 0; rr < 4; ++rr)
                out[(rbase + mt * 16 + lgrp * 4 + rr) * HH + w * 64 + nt * 16 + lrow] = acc[nt][rr];
    }
}

// ---------------------------------------------------------------------------
// Recurrence: 8 WGs x 16 batch rows; 256 threads = 4 waves (1/SIMD); wave w
// owns h-cols [w*64, w*64+64).  D[j][g] = sum_k W_h[k][j] * h[g][k].
// A-op = W_h^T f16 RESIDENT in VGPRs: wh[4][8] = 128 VGPRs; launch_bounds
// (256,1) gives the allocator ~512 VGPRs so it does NOT re-load W_h from
// memory every step (r4-r7 hidden cost: VGPR_Count 80-112 with >=130 live
// values proved the compiler was re-materializing weights per step).
// B-op = h f16 in swizzled LDS double buffer; 32 ds_read_b128/CU/step.
// C-init = xproj via running prefetch pointer (distance 2, parity regs xa/xb);
// last two steps peeled (no loads -> no alias clamp). 1 lgkm-only barrier/step.
// ---------------------------------------------------------------------------
template<bool PF>
static __device__ __forceinline__ void rec_step_full(
    const float* pld, float* pst,
    f32x4 (&xp)[4],                  // in: C-init for this step; out (PF): t+2
    const short* curb, short* nxtb,
    const f16x8 (&wh)[4][8], int lrow, int lgrp, int jb)
{
    // B-frags: h[g = lane&15][k = kc*32 + lgrp*8 + i] from swizzled LDS
    f16x8 bbf[8];
    #pragma unroll
    for (int kc = 0; kc < 8; ++kc) {
        unsigned off = (unsigned)(lrow * 512 + kc * 64 + lgrp * 16);
        off ^= (unsigned)((lrow & 7) << 4);
        bbf[kc] = *(const f16x8*)((const char*)curb + off);
    }

    f32x4 acc[4];
    #pragma unroll
    for (int mt = 0; mt < 4; ++mt) acc[mt] = xp[mt];

    if (PF) {
        #pragma unroll
        for (int mt = 0; mt < 4; ++mt)
            xp[mt] = *(const f32x4*)(pld + mt * 16);
    }

    // 4 independent chains x 8 deep
    #pragma unroll
    for (int kc = 0; kc < 8; ++kc)
        #pragma unroll
        for (int mt = 0; mt < 4; ++mt)
            acc[mt] = __builtin_amdgcn_mfma_f32_16x16x32_f16(wh[mt][kc], bbf[kc], acc[mt], 0, 0, 0);

    // tanh, store h_t to global (overwrites xp_t), write f16 h to next LDS buf
    #pragma unroll
    for (int mt = 0; mt < 4; ++mt) {
        f32x4 hv;
        #pragma unroll
        for (int rr = 0; rr < 4; ++rr) hv[rr] = fast_tanh(acc[mt][rr]);
        *(f32x4*)(pst + mt * 16) = hv;
        f16x4 q;
        #pragma unroll
        for (int rr = 0; rr < 4; ++rr) q[rr] = (_Float16)hv[rr];
        // D mapping: col g = lane&15 (batch row), row j = jb + mt*16 + lgrp*4 + rr
        unsigned off = (unsigned)(lrow * 512 + (jb + mt * 16 + lgrp * 4) * 2);
        off ^= (unsigned)((lrow & 7) << 4);
        *(f16x4*)((char*)nxtb + off) = q;
    }
    lds_barrier();
}

__global__ __launch_bounds__(256, 1) void rnn_rec_mfma(
    const float* __restrict__ h0, const float* __restrict__ W_h,
    float* io)
{
    __shared__ short hb0[16 * 256];  // f16 swizzled h, buffer 0 (8 KB)
    __shared__ short hb1[16 * 256];  // buffer 1
    const int tid  = threadIdx.x;
    const int lane = tid & 63;
    const int w    = tid >> 6;       // 0..3
    const int lrow = lane & 15;
    const int lgrp = lane >> 4;
    const int b0   = blockIdx.x * 16;
    const int jb   = w * 64;

    // A-frags: A[j][k] = W_h[k][j], j = jb + mt*16 + lrow, k = kc*32 + lgrp*8 + i
    f16x8 wh[4][8];
    #pragma unroll
    for (int mt = 0; mt < 4; ++mt) {
        const int j = jb + mt * 16 + lrow;
        #pragma unroll
        for (int kc = 0; kc < 8; ++kc)
            #pragma unroll
            for (int i = 0; i < 8; ++i)
                wh[mt][kc][i] = (_Float16)W_h[(kc * 32 + lgrp * 8 + i) * HH + j];
    }

    // h_lds[0] <- h0 (fp32 -> f16, swizzled); layout: [g][k], g = batch row
    {
        const int g  = tid >> 4;            // 0..15
        const int k0 = (tid & 15) * 16;     // 16 f16 per thread
        const float* hp = h0 + (b0 + g) * HH + k0;
        #pragma unroll
        for (int cc = 0; cc < 2; ++cc) {
            f16x8 p;
            #pragma unroll
            for (int i = 0; i < 8; ++i) p[i] = (_Float16)hp[cc * 8 + i];
            unsigned off = (unsigned)(g * 512 + k0 * 2 + cc * 16);
            off ^= (unsigned)((g & 7) << 4);
            *(f16x8*)((char*)hb0 + off) = p;
        }
    }

    // running pointers (strength-reduced): element offset for this thread
    const long S = (long)BB * HH;                         // per-step stride
    const long base = (long)(b0 + lrow) * HH + jb + lgrp * 4;
    const float* pld = io + base + 2 * S;                 // prefetch t+2
    float*       pst = io + base;                         // store t

    // xp preload (C-init) for t=0 / t=1 (distance-2 parity registers)
    f32x4 xa[4], xb[4];
    #pragma unroll
    for (int mt = 0; mt < 4; ++mt) {
        xa[mt] = *(const f32x4*)(io + base + 0 * S + mt * 16);
        xb[mt] = *(const f32x4*)(io + base + 1 * S + mt * 16);
    }

    __syncthreads();

    for (int t = 0; t < TT - 2; t += 2) {
        rec_step_full<true>(pld, pst, xa, hb0, hb1, wh, lrow, lgrp, jb);
        pld += S; pst += S;
        rec_step_full<true>(pld, pst, xb, hb1, hb0, wh, lrow, lgrp, jb);
        pld += S; pst += S;
    }
    // peeled final two steps: no prefetch loads (no OOB, no alias clamp)
    rec_step_full<false>(pld, pst, xa, hb0, hb1, wh, lrow, lgrp, jb);
    pst += S;
    rec_step_full<false>(pld, pst, xb, hb1, hb0, wh, lrow, lgrp, jb);
}

extern "C" void kernel_launch(void* const* d_in, const int* in_sizes, int n_in,
                              void* d_out, int out_size, void* d_ws, size_t ws_size,
                              hipStream_t stream) {
    const float* x    = (const float*)d_in[0];
    const float* h0   = (const float*)d_in[1];
    const float* W_in = (const float*)d_in[2];
    const float* b_in = (const float*)d_in[3];
    const float* W_h  = (const float*)d_in[4];
    const float* b_h  = (const float*)d_in[5];
    float* out = (float*)d_out;

    xproj_mfma<<<(TT * BB) / 64, 256, 0, stream>>>(x, W_in, b_in, b_h, out);
    rnn_rec_mfma<<<BB / 16, 256, 0, stream>>>(h0, W_h, out);
}